// Round 1
// 954.798 us; speedup vs baseline: 1.0103x; 1.0103x over previous
//
#include <hip/hip_runtime.h>
#include <math.h>

#define N_ROWS 262144
#define K_COMP 256
#define D_DIM  128
#define BN 64           // rows per block
#define BD 16           // d-tile
#define XS 68           // padded transposed-x row stride (16B-aligned, 2-way alias only)

static __device__ __constant__ float kLOG2PI = 1.8378770664093453f;

// ---------------- prep: B matrices, sigma, per-k constants, zero Q ----------------
__global__ __launch_bounds__(128) void gmm_prep(
    const float* __restrict__ means, const float* __restrict__ log_stds,
    const float* __restrict__ weights,
    float* __restrict__ ivT, float* __restrict__ m2T,
    float* __restrict__ sigma, float* __restrict__ ck, double* __restrict__ wsq)
{
    int k = blockIdx.x;     // 0..255
    int d = threadIdx.x;    // 0..127
    float ls = log_stds[k * D_DIM + d];
    float mu = means[k * D_DIM + d];
    float iv = expf(-2.0f * ls);
    ivT[d * K_COMP + k] = iv;
    m2T[d * K_COMP + k] = -2.0f * mu * iv;
    sigma[k * D_DIM + d] = expf(ls);

    float c = mu * mu * iv;
    float s = ls;
    float w1 = weights[d], w2 = weights[d + 128];
    float wm = fmaxf(w1, w2);

    __shared__ float red[8];
    int lane = d & 63, wv = d >> 6;
    #pragma unroll
    for (int o = 32; o > 0; o >>= 1) {
        c += __shfl_down(c, o, 64);
        s += __shfl_down(s, o, 64);
        wm = fmaxf(wm, __shfl_down(wm, o, 64));
    }
    if (lane == 0) { red[wv] = c; red[2 + wv] = s; red[4 + wv] = wm; }
    __syncthreads();
    float csum = red[0] + red[1];
    float ssum = red[2] + red[3];
    float wmax = fmaxf(red[4], red[5]);
    float we = expf(w1 - wmax) + expf(w2 - wmax);
    #pragma unroll
    for (int o = 32; o > 0; o >>= 1) we += __shfl_down(we, o, 64);
    if (lane == 0) red[6 + wv] = we;
    __syncthreads();
    if (d == 0) {
        float wsum = red[6] + red[7];
        float lw = weights[k] - (wmax + logf(wsum));   // log_softmax(weights)[k]
        ck[k] = -0.5f * (csum + (float)D_DIM * kLOG2PI) - ssum + lw;
        if (k == 0) *wsq = 0.0;
    }
}

// ---------------- main: quad GEMM + softmax/argmax + resample ----------------
// 256 threads, 64 rows x 256 cols per block, 8x8 per-thread tile.
// launch_bounds(256,2): VGPR budget 256. The 8x8 acc (64 regs) + unroll-4
// operand buffers (~96 regs) need ~160+ live regs; the previous (256,4)
// cap of 128 demoted acc to AGPR/scratch (VGPR_Count=64, WRITE_SIZE 19x
// over-write = spill traffic, VALU 2.2x the FMA floor). Let acc live in
// arch VGPRs; this kernel is ILP-rich and needs little TLP.
__global__ __launch_bounds__(256, 2) void gmm_main(
    const float* __restrict__ x, const float* __restrict__ noise,
    const float* __restrict__ means, const float* __restrict__ sigma,
    const float* __restrict__ ivT, const float* __restrict__ m2T,
    const float* __restrict__ ck,
    float* __restrict__ out_x, float* __restrict__ out_idx, double* __restrict__ wsq)
{
    __shared__ float sIv[BD * K_COMP];
    __shared__ float sM2[BD * K_COMP];
    __shared__ float sX [BD * XS];
    __shared__ float sCk[K_COMP];
    __shared__ int   sIdx[BN];
    __shared__ float sQ;

    const int tid = threadIdx.x;
    const int tx = tid & 31;      // col group: cols h*128 + tx*4 + j
    const int ty = tid >> 5;      // row group: rows ty*8 + rr  (ty 0..7)
    const long n0 = (long)blockIdx.x * BN;

    sCk[tid] = ck[tid];
    if (tid == 0) sQ = 0.0f;

    float acc[8][8];
    #pragma unroll
    for (int r = 0; r < 8; ++r)
        #pragma unroll
        for (int i = 0; i < 8; ++i) acc[r][i] = 0.0f;

    const int xr  = tid >> 2;          // staging row 0..63
    const int xc4 = (tid & 3) * 4;     // staging col 0,4,8,12

    #pragma unroll 1
    for (int d0 = 0; d0 < D_DIM; d0 += BD) {
        // ---- stage B tiles: float2 coalesced, 8 iters per array ----
        {
            const float2* gIv = (const float2*)&ivT[d0 * K_COMP];
            const float2* gM2 = (const float2*)&m2T[d0 * K_COMP];
            float2* lIv = (float2*)sIv;
            float2* lM2 = (float2*)sM2;
            #pragma unroll
            for (int it = 0; it < 8; ++it) {
                lIv[tid + it * 256] = gIv[tid + it * 256];
                lM2[tid + it * 256] = gM2[tid + it * 256];
            }
        }
        // ---- stage x tile transposed (squares computed later in regs) ----
        {
            float4 xv = *(const float4*)&x[(n0 + xr) * D_DIM + d0 + xc4];
            float xe[4] = {xv.x, xv.y, xv.z, xv.w};
            #pragma unroll
            for (int j = 0; j < 4; ++j)
                sX[(xc4 + j) * XS + xr] = xe[j];
        }
        __syncthreads();

        #pragma unroll 4
        for (int dd = 0; dd < BD; ++dd) {
            float4 xa = *(const float4*)&sX[dd * XS + ty * 8];
            float4 xb = *(const float4*)&sX[dd * XS + ty * 8 + 4];
            float xe[8]  = {xa.x, xa.y, xa.z, xa.w, xb.x, xb.y, xb.z, xb.w};
            float x2e[8];
            #pragma unroll
            for (int r = 0; r < 8; ++r) x2e[r] = xe[r] * xe[r];

            float4 iva = *(const float4*)&sIv[dd * K_COMP + tx * 4];
            float4 ivb = *(const float4*)&sIv[dd * K_COMP + 128 + tx * 4];
            float4 m2a = *(const float4*)&sM2[dd * K_COMP + tx * 4];
            float4 m2b = *(const float4*)&sM2[dd * K_COMP + 128 + tx * 4];
            float ive[8] = {iva.x, iva.y, iva.z, iva.w, ivb.x, ivb.y, ivb.z, ivb.w};
            float m2e[8] = {m2a.x, m2a.y, m2a.z, m2a.w, m2b.x, m2b.y, m2b.z, m2b.w};

            #pragma unroll
            for (int rr = 0; rr < 8; ++rr)
                #pragma unroll
                for (int i = 0; i < 8; ++i)
                    acc[rr][i] += x2e[rr] * ive[i] + xe[rr] * m2e[i];
        }
        __syncthreads();
    }

    // ---- epilogue phase 1: per-row softmax / argmax / Q ----
    float ckv[8];
    #pragma unroll
    for (int h = 0; h < 2; ++h)
        #pragma unroll
        for (int j = 0; j < 4; ++j) ckv[h * 4 + j] = sCk[h * 128 + tx * 4 + j];

    float qacc = 0.0f;
    #pragma unroll 1
    for (int rr = 0; rr < 8; ++rr) {
        float jv[8];
        float m = -INFINITY; int am = 0;
        #pragma unroll
        for (int i = 0; i < 8; ++i) {
            float v = -0.5f * acc[rr][i] + ckv[i];
            jv[i] = v;
            int c = (i >> 2) * 128 + tx * 4 + (i & 3);
            if (v > m || (v == m && c < am)) { m = v; am = c; }
        }
        #pragma unroll
        for (int o = 1; o < 32; o <<= 1) {
            float om = __shfl_xor(m, o, 32);
            int   oa = __shfl_xor(am, o, 32);
            if (om > m || (om == m && oa < am)) { m = om; am = oa; }
        }
        float es = 0.0f, qs = 0.0f;
        #pragma unroll
        for (int i = 0; i < 8; ++i) {
            float e = expf(jv[i] - m);
            es += e; qs += e * jv[i];
        }
        #pragma unroll
        for (int o = 1; o < 32; o <<= 1) {
            es += __shfl_xor(es, o, 32);
            qs += __shfl_xor(qs, o, 32);
        }
        qacc += qs / es;
        if (tx == 0) sIdx[ty * 8 + rr] = am;
    }

    // Q: both 32-lane groups of a wave hold their own group sums; fold, then block-reduce
    qacc += __shfl_xor(qacc, 32, 64);
    if ((tid & 63) == 0) atomicAdd(&sQ, qacc);
    __syncthreads();
    if (tid == 0) atomicAdd(wsq, (double)sQ);

    // ---- epilogue phase 2: wave-contiguous resample writes ----
    const int wv = tid >> 6, lane = tid & 63;
    #pragma unroll 4
    for (int r16 = 0; r16 < 16; ++r16) {
        const int row = wv * 16 + r16;
        const int idx = sIdx[row];
        const long n = n0 + row;
        float2 mv = *(const float2*)&means[idx * D_DIM + lane * 2];
        float2 sv = *(const float2*)&sigma[idx * D_DIM + lane * 2];
        float2 nv = *(const float2*)&noise[n * D_DIM + lane * 2];
        float2 ov;
        ov.x = mv.x + sv.x * nv.x * 0.1f;
        ov.y = mv.y + sv.y * nv.y * 0.1f;
        *(float2*)&out_x[n * D_DIM + lane * 2] = ov;
    }
    if (tid < BN) out_idx[n0 + tid] = (float)sIdx[tid];
}

__global__ void gmm_finalize(const double* __restrict__ wsq, float* __restrict__ out_q)
{
    *out_q = (float)(*wsq * (1.0 / ((double)N_ROWS * (double)K_COMP)));
}

extern "C" void kernel_launch(void* const* d_in, const int* in_sizes, int n_in,
                              void* d_out, int out_size, void* d_ws, size_t ws_size,
                              hipStream_t stream)
{
    const float* x        = (const float*)d_in[0];
    const float* means    = (const float*)d_in[1];
    const float* log_stds = (const float*)d_in[2];
    const float* weights  = (const float*)d_in[3];
    const float* noise    = (const float*)d_in[4];

    float* out_x   = (float*)d_out;                          // [N, D]
    float* out_idx = (float*)d_out + (size_t)N_ROWS * D_DIM; // [N]
    float* out_q   = out_idx + N_ROWS;                       // scalar

    // ws layout (floats): ivT[128*256] | m2T[128*256] | sigma[256*128] | ck[256] | (double) wsq
    float* ws    = (float*)d_ws;
    float* ivT   = ws;
    float* m2T   = ws + 32768;
    float* sigma = ws + 65536;
    float* ck    = ws + 98304;
    double* wsq  = (double*)(ws + 98560);

    hipLaunchKernelGGL(gmm_prep, dim3(K_COMP), dim3(D_DIM), 0, stream,
                       means, log_stds, weights, ivT, m2T, sigma, ck, wsq);
    hipLaunchKernelGGL(gmm_main, dim3(N_ROWS / BN), dim3(256), 0, stream,
                       x, noise, means, sigma, ivT, m2T, ck, out_x, out_idx, wsq);
    hipLaunchKernelGGL(gmm_finalize, dim3(1), dim3(1), 0, stream, wsq, out_q);
}

// Round 2
// 810.384 us; speedup vs baseline: 1.1903x; 1.1782x over previous
//
#include <hip/hip_runtime.h>
#include <math.h>

#define N_ROWS 262144
#define K_COMP 256
#define D_DIM  128
#define BN 64           // rows per block
#define BD 16           // d-tile
#define XS 68           // padded transposed-x row stride (16B-aligned, 2-way alias only)

static __device__ __constant__ float kLOG2PI = 1.8378770664093453f;

// ---------------- prep: B matrices, sigma, per-k constants, zero Q ----------------
__global__ __launch_bounds__(128) void gmm_prep(
    const float* __restrict__ means, const float* __restrict__ log_stds,
    const float* __restrict__ weights,
    float* __restrict__ ivT, float* __restrict__ m2T,
    float* __restrict__ sigma, float* __restrict__ ck, double* __restrict__ wsq)
{
    int k = blockIdx.x;     // 0..255
    int d = threadIdx.x;    // 0..127
    float ls = log_stds[k * D_DIM + d];
    float mu = means[k * D_DIM + d];
    float iv = expf(-2.0f * ls);
    ivT[d * K_COMP + k] = iv;
    m2T[d * K_COMP + k] = -2.0f * mu * iv;
    sigma[k * D_DIM + d] = expf(ls);

    float c = mu * mu * iv;
    float s = ls;
    float w1 = weights[d], w2 = weights[d + 128];
    float wm = fmaxf(w1, w2);

    __shared__ float red[8];
    int lane = d & 63, wv = d >> 6;
    #pragma unroll
    for (int o = 32; o > 0; o >>= 1) {
        c += __shfl_down(c, o, 64);
        s += __shfl_down(s, o, 64);
        wm = fmaxf(wm, __shfl_down(wm, o, 64));
    }
    if (lane == 0) { red[wv] = c; red[2 + wv] = s; red[4 + wv] = wm; }
    __syncthreads();
    float csum = red[0] + red[1];
    float ssum = red[2] + red[3];
    float wmax = fmaxf(red[4], red[5]);
    float we = expf(w1 - wmax) + expf(w2 - wmax);
    #pragma unroll
    for (int o = 32; o > 0; o >>= 1) we += __shfl_down(we, o, 64);
    if (lane == 0) red[6 + wv] = we;
    __syncthreads();
    if (d == 0) {
        float wsum = red[6] + red[7];
        float lw = weights[k] - (wmax + logf(wsum));   // log_softmax(weights)[k]
        ck[k] = -0.5f * (csum + (float)D_DIM * kLOG2PI) - ssum + lw;
        if (k == 0) *wsq = 0.0;
    }
}

// ---------------- main: quad GEMM + softmax/argmax + resample ----------------
// 256 threads, 64 rows x 256 cols per block, 8x8 per-thread tile.
// CRITICAL: every access to acc[][] must use compile-time-constant indices
// (epilogue rr loop FULLY unrolled). A runtime index anywhere demotes the
// whole acc array to scratch (rule #20) -> 2.3 GB of HBM spill writes,
// which is exactly what rounds 0-1 measured (WRITE_SIZE 2.49e6 KB, VGPR=64).
__global__ __launch_bounds__(256, 2) void gmm_main(
    const float* __restrict__ x, const float* __restrict__ noise,
    const float* __restrict__ means, const float* __restrict__ sigma,
    const float* __restrict__ ivT, const float* __restrict__ m2T,
    const float* __restrict__ ck,
    float* __restrict__ out_x, float* __restrict__ out_idx, double* __restrict__ wsq)
{
    __shared__ float sIv[BD * K_COMP];
    __shared__ float sM2[BD * K_COMP];
    __shared__ float sX [BD * XS];
    __shared__ float sCk[K_COMP];
    __shared__ int   sIdx[BN];
    __shared__ float sQ;

    const int tid = threadIdx.x;
    const int tx = tid & 31;      // col group: cols h*128 + tx*4 + j
    const int ty = tid >> 5;      // row group: rows ty*8 + rr  (ty 0..7)
    const long n0 = (long)blockIdx.x * BN;

    sCk[tid] = ck[tid];
    if (tid == 0) sQ = 0.0f;

    float acc[8][8];
    #pragma unroll
    for (int r = 0; r < 8; ++r)
        #pragma unroll
        for (int i = 0; i < 8; ++i) acc[r][i] = 0.0f;

    const int xr  = tid >> 2;          // staging row 0..63
    const int xc4 = (tid & 3) * 4;     // staging col 0,4,8,12

    #pragma unroll 1
    for (int d0 = 0; d0 < D_DIM; d0 += BD) {
        // ---- stage B tiles: float2 coalesced, 8 iters per array ----
        {
            const float2* gIv = (const float2*)&ivT[d0 * K_COMP];
            const float2* gM2 = (const float2*)&m2T[d0 * K_COMP];
            float2* lIv = (float2*)sIv;
            float2* lM2 = (float2*)sM2;
            #pragma unroll
            for (int it = 0; it < 8; ++it) {
                lIv[tid + it * 256] = gIv[tid + it * 256];
                lM2[tid + it * 256] = gM2[tid + it * 256];
            }
        }
        // ---- stage x tile transposed (squares computed later in regs) ----
        {
            float4 xv = *(const float4*)&x[(n0 + xr) * D_DIM + d0 + xc4];
            float xe[4] = {xv.x, xv.y, xv.z, xv.w};
            #pragma unroll
            for (int j = 0; j < 4; ++j)
                sX[(xc4 + j) * XS + xr] = xe[j];
        }
        __syncthreads();

        #pragma unroll 4
        for (int dd = 0; dd < BD; ++dd) {
            float4 xa = *(const float4*)&sX[dd * XS + ty * 8];
            float4 xb = *(const float4*)&sX[dd * XS + ty * 8 + 4];
            float xe[8]  = {xa.x, xa.y, xa.z, xa.w, xb.x, xb.y, xb.z, xb.w};
            float x2e[8];
            #pragma unroll
            for (int r = 0; r < 8; ++r) x2e[r] = xe[r] * xe[r];

            float4 iva = *(const float4*)&sIv[dd * K_COMP + tx * 4];
            float4 ivb = *(const float4*)&sIv[dd * K_COMP + 128 + tx * 4];
            float4 m2a = *(const float4*)&sM2[dd * K_COMP + tx * 4];
            float4 m2b = *(const float4*)&sM2[dd * K_COMP + 128 + tx * 4];
            float ive[8] = {iva.x, iva.y, iva.z, iva.w, ivb.x, ivb.y, ivb.z, ivb.w};
            float m2e[8] = {m2a.x, m2a.y, m2a.z, m2a.w, m2b.x, m2b.y, m2b.z, m2b.w};

            #pragma unroll
            for (int rr = 0; rr < 8; ++rr)
                #pragma unroll
                for (int i = 0; i < 8; ++i)
                    acc[rr][i] += x2e[rr] * ive[i] + xe[rr] * m2e[i];
        }
        __syncthreads();
    }

    // ---- epilogue phase 1: per-row softmax / argmax / Q ----
    // FULLY unrolled over rr so acc[rr][i] is always a static index.
    float ckv[8];
    #pragma unroll
    for (int h = 0; h < 2; ++h)
        #pragma unroll
        for (int j = 0; j < 4; ++j) ckv[h * 4 + j] = sCk[h * 128 + tx * 4 + j];

    float qacc = 0.0f;
    #pragma unroll
    for (int rr = 0; rr < 8; ++rr) {
        float jv[8];
        float m = -INFINITY; int am = 0;
        #pragma unroll
        for (int i = 0; i < 8; ++i) {
            float v = -0.5f * acc[rr][i] + ckv[i];
            jv[i] = v;
            int c = (i >> 2) * 128 + tx * 4 + (i & 3);
            if (v > m || (v == m && c < am)) { m = v; am = c; }
        }
        #pragma unroll
        for (int o = 1; o < 32; o <<= 1) {
            float om = __shfl_xor(m, o, 32);
            int   oa = __shfl_xor(am, o, 32);
            if (om > m || (om == m && oa < am)) { m = om; am = oa; }
        }
        float es = 0.0f, qs = 0.0f;
        #pragma unroll
        for (int i = 0; i < 8; ++i) {
            float e = expf(jv[i] - m);
            es += e; qs += e * jv[i];
        }
        #pragma unroll
        for (int o = 1; o < 32; o <<= 1) {
            es += __shfl_xor(es, o, 32);
            qs += __shfl_xor(qs, o, 32);
        }
        qacc += qs / es;
        if (tx == 0) sIdx[ty * 8 + rr] = am;
    }

    // Q: both 32-lane groups of a wave hold their own group sums; fold, then block-reduce
    qacc += __shfl_xor(qacc, 32, 64);
    if ((tid & 63) == 0) atomicAdd(&sQ, qacc);
    __syncthreads();
    if (tid == 0) atomicAdd(wsq, (double)sQ);

    // ---- epilogue phase 2: wave-contiguous resample writes ----
    const int wv = tid >> 6, lane = tid & 63;
    #pragma unroll 4
    for (int r16 = 0; r16 < 16; ++r16) {
        const int row = wv * 16 + r16;
        const int idx = sIdx[row];
        const long n = n0 + row;
        float2 mv = *(const float2*)&means[idx * D_DIM + lane * 2];
        float2 sv = *(const float2*)&sigma[idx * D_DIM + lane * 2];
        float2 nv = *(const float2*)&noise[n * D_DIM + lane * 2];
        float2 ov;
        ov.x = mv.x + sv.x * nv.x * 0.1f;
        ov.y = mv.y + sv.y * nv.y * 0.1f;
        *(float2*)&out_x[n * D_DIM + lane * 2] = ov;
    }
    if (tid < BN) out_idx[n0 + tid] = (float)sIdx[tid];
}

__global__ void gmm_finalize(const double* __restrict__ wsq, float* __restrict__ out_q)
{
    *out_q = (float)(*wsq * (1.0 / ((double)N_ROWS * (double)K_COMP)));
}

extern "C" void kernel_launch(void* const* d_in, const int* in_sizes, int n_in,
                              void* d_out, int out_size, void* d_ws, size_t ws_size,
                              hipStream_t stream)
{
    const float* x        = (const float*)d_in[0];
    const float* means    = (const float*)d_in[1];
    const float* log_stds = (const float*)d_in[2];
    const float* weights  = (const float*)d_in[3];
    const float* noise    = (const float*)d_in[4];

    float* out_x   = (float*)d_out;                          // [N, D]
    float* out_idx = (float*)d_out + (size_t)N_ROWS * D_DIM; // [N]
    float* out_q   = out_idx + N_ROWS;                       // scalar

    // ws layout (floats): ivT[128*256] | m2T[128*256] | sigma[256*128] | ck[256] | (double) wsq
    float* ws    = (float*)d_ws;
    float* ivT   = ws;
    float* m2T   = ws + 32768;
    float* sigma = ws + 65536;
    float* ck    = ws + 98304;
    double* wsq  = (double*)(ws + 98560);

    hipLaunchKernelGGL(gmm_prep, dim3(K_COMP), dim3(D_DIM), 0, stream,
                       means, log_stds, weights, ivT, m2T, sigma, ck, wsq);
    hipLaunchKernelGGL(gmm_main, dim3(N_ROWS / BN), dim3(256), 0, stream,
                       x, noise, means, sigma, ivT, m2T, ck, out_x, out_idx, wsq);
    hipLaunchKernelGGL(gmm_finalize, dim3(1), dim3(1), 0, stream, wsq, out_q);
}

// Round 3
// 664.144 us; speedup vs baseline: 1.4524x; 1.2202x over previous
//
#include <hip/hip_runtime.h>
#include <math.h>

#define N_ROWS 262144
#define K_COMP 256
#define D_DIM  128
#define BN 64           // rows per block
#define BD 16           // d-tile
#define XS 68           // padded transposed-x row stride (16B-aligned, 2-way alias only)

static __device__ __constant__ float kLOG2PI = 1.8378770664093453f;

// ---------------- prep: B matrices, sigma, per-k constants, zero Q ----------------
__global__ __launch_bounds__(128) void gmm_prep(
    const float* __restrict__ means, const float* __restrict__ log_stds,
    const float* __restrict__ weights,
    float* __restrict__ ivT, float* __restrict__ m2T,
    float* __restrict__ sigma, float* __restrict__ ck, double* __restrict__ wsq)
{
    int k = blockIdx.x;     // 0..255
    int d = threadIdx.x;    // 0..127
    float ls = log_stds[k * D_DIM + d];
    float mu = means[k * D_DIM + d];
    float iv = expf(-2.0f * ls);
    ivT[d * K_COMP + k] = iv;
    m2T[d * K_COMP + k] = -2.0f * mu * iv;
    sigma[k * D_DIM + d] = expf(ls);

    float c = mu * mu * iv;
    float s = ls;
    float w1 = weights[d], w2 = weights[d + 128];
    float wm = fmaxf(w1, w2);

    __shared__ float red[8];
    int lane = d & 63, wv = d >> 6;
    #pragma unroll
    for (int o = 32; o > 0; o >>= 1) {
        c += __shfl_down(c, o, 64);
        s += __shfl_down(s, o, 64);
        wm = fmaxf(wm, __shfl_down(wm, o, 64));
    }
    if (lane == 0) { red[wv] = c; red[2 + wv] = s; red[4 + wv] = wm; }
    __syncthreads();
    float csum = red[0] + red[1];
    float ssum = red[2] + red[3];
    float wmax = fmaxf(red[4], red[5]);
    float we = expf(w1 - wmax) + expf(w2 - wmax);
    #pragma unroll
    for (int o = 32; o > 0; o >>= 1) we += __shfl_down(we, o, 64);
    if (lane == 0) red[6 + wv] = we;
    __syncthreads();
    if (d == 0) {
        float wsum = red[6] + red[7];
        float lw = weights[k] - (wmax + logf(wsum));   // log_softmax(weights)[k]
        ck[k] = -0.5f * (csum + (float)D_DIM * kLOG2PI) - ssum + lw;
        if (k == 0) *wsq = 0.0;
    }
}

// ---------------- main: quad GEMM + softmax/argmax + resample ----------------
// 256 threads, 64 rows x 256 cols per block, 8x8 per-thread tile.
// Rules learned on this kernel:
//  - acc[][] must only ever be indexed with compile-time constants (rule #20):
//    a runtime index demoted it to scratch -> 2.3 GB HBM spill (rounds 0-1).
//  - accumulate via explicit fmaf: `acc += a*b + c*d` compiles to mul+fma+ADD
//    (3 VALU) under contract-without-reassoc; two fmaf's give 2 VALU.
//  - B-tile staging via global_load_lds (16B): no VGPR round-trip, no ds_write,
//    layout is linear so the wave-uniform-base + lane*16 constraint is met.
__global__ __launch_bounds__(256, 2) void gmm_main(
    const float* __restrict__ x, const float* __restrict__ noise,
    const float* __restrict__ means, const float* __restrict__ sigma,
    const float* __restrict__ ivT, const float* __restrict__ m2T,
    const float* __restrict__ ck,
    float* __restrict__ out_x, float* __restrict__ out_idx, double* __restrict__ wsq)
{
    __shared__ float sIv[BD * K_COMP];
    __shared__ float sM2[BD * K_COMP];
    __shared__ float sX [BD * XS];
    __shared__ float sCk[K_COMP];
    __shared__ int   sIdx[BN];
    __shared__ float sQ;

    const int tid = threadIdx.x;
    const int tx = tid & 31;      // col group: cols h*128 + tx*4 + j
    const int ty = tid >> 5;      // row group: rows ty*8 + rr  (ty 0..7)
    const long n0 = (long)blockIdx.x * BN;

    sCk[tid] = ck[tid];
    if (tid == 0) sQ = 0.0f;

    float acc[8][8];
    #pragma unroll
    for (int r = 0; r < 8; ++r)
        #pragma unroll
        for (int i = 0; i < 8; ++i) acc[r][i] = 0.0f;

    const int xr  = tid >> 2;          // staging row 0..63
    const int xc4 = (tid & 3) * 4;     // staging col 0,4,8,12
    const int wvbase = (tid >> 6) * 256;   // wave-uniform LDS float offset for global_load_lds

    #pragma unroll 1
    for (int d0 = 0; d0 < D_DIM; d0 += BD) {
        // ---- stage B tiles: async global->LDS, 16B per lane, linear layout ----
        {
            const float* gIv = ivT + d0 * K_COMP;
            const float* gM2 = m2T + d0 * K_COMP;
            #pragma unroll
            for (int it = 0; it < 4; ++it) {
                __builtin_amdgcn_global_load_lds(
                    (const __attribute__((address_space(1))) void*)(gIv + it * 1024 + tid * 4),
                    (__attribute__((address_space(3))) void*)(sIv + it * 1024 + wvbase),
                    16, 0, 0);
                __builtin_amdgcn_global_load_lds(
                    (const __attribute__((address_space(1))) void*)(gM2 + it * 1024 + tid * 4),
                    (__attribute__((address_space(3))) void*)(sM2 + it * 1024 + wvbase),
                    16, 0, 0);
            }
        }
        // ---- stage x tile transposed (squares computed later in regs) ----
        {
            float4 xv = *(const float4*)&x[(n0 + xr) * D_DIM + d0 + xc4];
            float xe[4] = {xv.x, xv.y, xv.z, xv.w};
            #pragma unroll
            for (int j = 0; j < 4; ++j)
                sX[(xc4 + j) * XS + xr] = xe[j];
        }
        __syncthreads();

        #pragma unroll 4
        for (int dd = 0; dd < BD; ++dd) {
            float4 xa = *(const float4*)&sX[dd * XS + ty * 8];
            float4 xb = *(const float4*)&sX[dd * XS + ty * 8 + 4];
            float xe[8]  = {xa.x, xa.y, xa.z, xa.w, xb.x, xb.y, xb.z, xb.w};
            float x2e[8];
            #pragma unroll
            for (int r = 0; r < 8; ++r) x2e[r] = xe[r] * xe[r];

            float4 iva = *(const float4*)&sIv[dd * K_COMP + tx * 4];
            float4 ivb = *(const float4*)&sIv[dd * K_COMP + 128 + tx * 4];
            float4 m2a = *(const float4*)&sM2[dd * K_COMP + tx * 4];
            float4 m2b = *(const float4*)&sM2[dd * K_COMP + 128 + tx * 4];
            float ive[8] = {iva.x, iva.y, iva.z, iva.w, ivb.x, ivb.y, ivb.z, ivb.w};
            float m2e[8] = {m2a.x, m2a.y, m2a.z, m2a.w, m2b.x, m2b.y, m2b.z, m2b.w};

            #pragma unroll
            for (int rr = 0; rr < 8; ++rr)
                #pragma unroll
                for (int i = 0; i < 8; ++i) {
                    // two v_fmac, NOT mul+fma+add
                    acc[rr][i] = fmaf(x2e[rr], ive[i], acc[rr][i]);
                    acc[rr][i] = fmaf(xe[rr],  m2e[i], acc[rr][i]);
                }
        }
        __syncthreads();
    }

    // ---- epilogue phase 1: per-row softmax / argmax / Q ----
    // FULLY unrolled over rr so acc[rr][i] is always a static index.
    float ckv[8];
    #pragma unroll
    for (int h = 0; h < 2; ++h)
        #pragma unroll
        for (int j = 0; j < 4; ++j) ckv[h * 4 + j] = sCk[h * 128 + tx * 4 + j];

    float qacc = 0.0f;
    #pragma unroll
    for (int rr = 0; rr < 8; ++rr) {
        float jv[8];
        float m = -INFINITY; int am = 0;
        #pragma unroll
        for (int i = 0; i < 8; ++i) {
            float v = fmaf(-0.5f, acc[rr][i], ckv[i]);
            jv[i] = v;
            int c = (i >> 2) * 128 + tx * 4 + (i & 3);
            if (v > m || (v == m && c < am)) { m = v; am = c; }
        }
        #pragma unroll
        for (int o = 1; o < 32; o <<= 1) {
            float om = __shfl_xor(m, o, 32);
            int   oa = __shfl_xor(am, o, 32);
            if (om > m || (om == m && oa < am)) { m = om; am = oa; }
        }
        float es = 0.0f, qs = 0.0f;
        #pragma unroll
        for (int i = 0; i < 8; ++i) {
            float e = expf(jv[i] - m);
            es += e; qs += e * jv[i];
        }
        #pragma unroll
        for (int o = 1; o < 32; o <<= 1) {
            es += __shfl_xor(es, o, 32);
            qs += __shfl_xor(qs, o, 32);
        }
        qacc += qs / es;
        if (tx == 0) sIdx[ty * 8 + rr] = am;
    }

    // Q: both 32-lane groups of a wave hold their own group sums; fold, then block-reduce
    qacc += __shfl_xor(qacc, 32, 64);
    if ((tid & 63) == 0) atomicAdd(&sQ, qacc);
    __syncthreads();
    if (tid == 0) atomicAdd(wsq, (double)sQ);

    // ---- epilogue phase 2: wave-contiguous resample writes ----
    const int wv = tid >> 6, lane = tid & 63;
    #pragma unroll 4
    for (int r16 = 0; r16 < 16; ++r16) {
        const int row = wv * 16 + r16;
        const int idx = sIdx[row];
        const long n = n0 + row;
        float2 mv = *(const float2*)&means[idx * D_DIM + lane * 2];
        float2 sv = *(const float2*)&sigma[idx * D_DIM + lane * 2];
        float2 nv = *(const float2*)&noise[n * D_DIM + lane * 2];
        float2 ov;
        ov.x = mv.x + sv.x * nv.x * 0.1f;
        ov.y = mv.y + sv.y * nv.y * 0.1f;
        *(float2*)&out_x[n * D_DIM + lane * 2] = ov;
    }
    if (tid < BN) out_idx[n0 + tid] = (float)sIdx[tid];
}

__global__ void gmm_finalize(const double* __restrict__ wsq, float* __restrict__ out_q)
{
    *out_q = (float)(*wsq * (1.0 / ((double)N_ROWS * (double)K_COMP)));
}

extern "C" void kernel_launch(void* const* d_in, const int* in_sizes, int n_in,
                              void* d_out, int out_size, void* d_ws, size_t ws_size,
                              hipStream_t stream)
{
    const float* x        = (const float*)d_in[0];
    const float* means    = (const float*)d_in[1];
    const float* log_stds = (const float*)d_in[2];
    const float* weights  = (const float*)d_in[3];
    const float* noise    = (const float*)d_in[4];

    float* out_x   = (float*)d_out;                          // [N, D]
    float* out_idx = (float*)d_out + (size_t)N_ROWS * D_DIM; // [N]
    float* out_q   = out_idx + N_ROWS;                       // scalar

    // ws layout (floats): ivT[128*256] | m2T[128*256] | sigma[256*128] | ck[256] | (double) wsq
    float* ws    = (float*)d_ws;
    float* ivT   = ws;
    float* m2T   = ws + 32768;
    float* sigma = ws + 65536;
    float* ck    = ws + 98304;
    double* wsq  = (double*)(ws + 98560);

    hipLaunchKernelGGL(gmm_prep, dim3(K_COMP), dim3(D_DIM), 0, stream,
                       means, log_stds, weights, ivT, m2T, sigma, ck, wsq);
    hipLaunchKernelGGL(gmm_main, dim3(N_ROWS / BN), dim3(256), 0, stream,
                       x, noise, means, sigma, ivT, m2T, ck, out_x, out_idx, wsq);
    hipLaunchKernelGGL(gmm_finalize, dim3(1), dim3(1), 0, stream, wsq, out_q);
}

// Round 4
// 461.235 us; speedup vs baseline: 2.0914x; 1.4399x over previous
//
#include <hip/hip_runtime.h>
#include <math.h>

#define N_ROWS 262144
#define K_COMP 256
#define D_DIM  128
#define BN 64           // rows per block
#define KIN 256         // GEMM inner dim = concat(x^2 | x)

typedef _Float16 half8v __attribute__((ext_vector_type(8)));
typedef _Float16 half4v __attribute__((ext_vector_type(4)));
typedef float    f32x4  __attribute__((ext_vector_type(4)));

static __device__ __constant__ float kLOG2PI = 1.8378770664093453f;

// ---------------- prep ----------------
// Writes B = [iv | m2] (K_COMP x KIN) as fp16 hi/lo in FRAGMENT-LINEAR layout:
// element (comp k, kin) -> lin = ((c*8+s)*64 + l)*8 + j  where
//   c = k>>4 (col-frag), s = kin>>5 (k-step),
//   l = ((kin>>3)&3)*16 + (k&15)  (the lane that owns it),
//   j = kin&7 (element within the lane's 16B).
// Main kernel then loads B fragments from global with ONE coalesced
// global_load_dwordx4 per fragment (B is 256KB, L2-resident).
__global__ __launch_bounds__(128) void gmm_prep(
    const float* __restrict__ means, const float* __restrict__ log_stds,
    const float* __restrict__ weights,
    _Float16* __restrict__ Bhi, _Float16* __restrict__ Blo,
    float* __restrict__ sigma, float* __restrict__ ck, double* __restrict__ wsq)
{
    int k = blockIdx.x;     // 0..255
    int d = threadIdx.x;    // 0..127
    float ls = log_stds[k * D_DIM + d];
    float mu = means[k * D_DIM + d];
    float iv = expf(-2.0f * ls);
    float m2 = -2.0f * mu * iv;
    sigma[k * D_DIM + d] = expf(ls);

    // fragment-linear hi/lo writes for kin=d (iv) and kin=128+d (m2)
    {
        int c = k >> 4;
        #pragma unroll
        for (int t = 0; t < 2; ++t) {
            int kin = t * 128 + d;
            float val = t ? m2 : iv;
            int s = kin >> 5;
            int l = ((kin >> 3) & 3) * 16 + (k & 15);
            int j = kin & 7;
            int lin = ((c * 8 + s) * 64 + l) * 8 + j;
            _Float16 hi = (_Float16)val;
            Bhi[lin] = hi;
            Blo[lin] = (_Float16)(val - (float)hi);
        }
    }

    float c = mu * mu * iv;
    float s = ls;
    float w1 = weights[d], w2 = weights[d + 128];
    float wm = fmaxf(w1, w2);

    __shared__ float red[8];
    int lane = d & 63, wv = d >> 6;
    #pragma unroll
    for (int o = 32; o > 0; o >>= 1) {
        c += __shfl_down(c, o, 64);
        s += __shfl_down(s, o, 64);
        wm = fmaxf(wm, __shfl_down(wm, o, 64));
    }
    if (lane == 0) { red[wv] = c; red[2 + wv] = s; red[4 + wv] = wm; }
    __syncthreads();
    float csum = red[0] + red[1];
    float ssum = red[2] + red[3];
    float wmax = fmaxf(red[4], red[5]);
    float we = expf(w1 - wmax) + expf(w2 - wmax);
    #pragma unroll
    for (int o = 32; o > 0; o >>= 1) we += __shfl_down(we, o, 64);
    if (lane == 0) red[6 + wv] = we;
    __syncthreads();
    if (d == 0) {
        float wsum = red[6] + red[7];
        float lw = weights[k] - (wmax + logf(wsum));   // log_softmax(weights)[k]
        ck[k] = -0.5f * (csum + (float)D_DIM * kLOG2PI) - ssum + lw;
        if (k == 0) *wsq = 0.0;
    }
}

// ---------------- main: MFMA quad GEMM + softmax/argmax + resample ----------------
// fp32 GEMM emulated as fp16 split-2 x 3 MFMA passes (hi*hi + hi*lo + lo*hi);
// error ~2^-23 relative, same order as fp32 summation-order noise.
// 4 waves; wave w owns cols [64w,64w+64), all 64 rows: 4x4 fragments of 16x16.
// A staged once in LDS (fp16 hi/lo, XOR-swizzled (row&7)<<4 to kill the
// 512B-row-stride 16-way bank conflict); B fragments straight from global
// (fragment-linear, coalesced). NO barriers inside the k-loop.
__global__ __launch_bounds__(256, 2) void gmm_main(
    const float* __restrict__ x, const float* __restrict__ noise,
    const float* __restrict__ means, const float* __restrict__ sigma,
    const _Float16* __restrict__ Bhi, const _Float16* __restrict__ Blo,
    const float* __restrict__ ck,
    float* __restrict__ out_x, float* __restrict__ out_idx, double* __restrict__ wsq)
{
    __shared__ char  sA[2][BN * 512];      // [hi|lo][row][256 halves], swizzled
    __shared__ float sCk[K_COMP];
    __shared__ float sMax[BN][4];
    __shared__ int   sAm [BN][4];
    __shared__ float sEs [BN][4];
    __shared__ float sQs [BN][4];
    __shared__ int   sIdx[BN];

    const int tid = threadIdx.x;
    const int w   = tid >> 6;      // wave 0..3
    const int l   = tid & 63;      // lane
    const int lm  = l & 15;
    const int lh  = l >> 4;
    const long n0 = (long)blockIdx.x * BN;

    sCk[tid] = ck[tid];

    // ---- stage A: x-tile -> fp16 hi/lo (x^2 seg0, x seg1), swizzled ----
    {
        const float4* xg = (const float4*)(x + (size_t)n0 * D_DIM);
        #pragma unroll
        for (int it = 0; it < 8; ++it) {
            int g = it * 256 + tid;
            int row = g >> 5, d4 = g & 31;         // d = d4*4
            float4 xv = xg[g];
            float xe[4] = {xv.x, xv.y, xv.z, xv.w};
            half4v x2h, x2l, xh, xl;
            #pragma unroll
            for (int cc = 0; cc < 4; ++cc) {
                float v = xe[cc], vv = v * v;
                _Float16 a = (_Float16)vv;
                x2h[cc] = a; x2l[cc] = (_Float16)(vv - (float)a);
                _Float16 b = (_Float16)v;
                xh[cc] = b;  xl[cc] = (_Float16)(v - (float)b);
            }
            unsigned sw = (unsigned)(row & 7) << 4;
            unsigned o0 = ((unsigned)(row * 512 + d4 * 8)) ^ sw;        // seg0: kin=d
            unsigned o1 = ((unsigned)(row * 512 + 256 + d4 * 8)) ^ sw;  // seg1: kin=128+d
            *(half4v*)(sA[0] + o0) = x2h;
            *(half4v*)(sA[0] + o1) = xh;
            *(half4v*)(sA[1] + o0) = x2l;
            *(half4v*)(sA[1] + o1) = xl;
        }
    }
    __syncthreads();

    // ---- MFMA k-loop: 8 steps x 16 frags x 3 passes ----
    f32x4 acc[4][4];
    #pragma unroll
    for (int rf = 0; rf < 4; ++rf)
        #pragma unroll
        for (int cf = 0; cf < 4; ++cf)
            acc[rf][cf] = (f32x4){0.0f, 0.0f, 0.0f, 0.0f};

    const half8v* Bh = (const half8v*)Bhi;
    const half8v* Bl = (const half8v*)Blo;

    #pragma unroll 2
    for (int s = 0; s < 8; ++s) {
        half8v ah[4], al[4], bh[4], bl[4];
        #pragma unroll
        for (int rf = 0; rf < 4; ++rf) {
            int row = rf * 16 + lm;                // A-operand: row = lane&15
            unsigned off = ((unsigned)(row * 512 + s * 64 + lh * 16))
                         ^ ((unsigned)(row & 7) << 4);
            ah[rf] = *(const half8v*)(sA[0] + off);
            al[rf] = *(const half8v*)(sA[1] + off);
        }
        #pragma unroll
        for (int cf = 0; cf < 4; ++cf) {
            int cgl = w * 4 + cf;                  // global col-frag
            int bidx = (cgl * 8 + s) * 64 + l;
            bh[cf] = Bh[bidx];
            bl[cf] = Bl[bidx];
        }
        #pragma unroll
        for (int rf = 0; rf < 4; ++rf)
            #pragma unroll
            for (int cf = 0; cf < 4; ++cf) {
                acc[rf][cf] = __builtin_amdgcn_mfma_f32_16x16x32_f16(ah[rf], bh[cf], acc[rf][cf], 0, 0, 0);
                acc[rf][cf] = __builtin_amdgcn_mfma_f32_16x16x32_f16(ah[rf], bl[cf], acc[rf][cf], 0, 0, 0);
                acc[rf][cf] = __builtin_amdgcn_mfma_f32_16x16x32_f16(al[rf], bh[cf], acc[rf][cf], 0, 0, 0);
            }
    }

    // ---- epilogue 1: per-row softmax/argmax partials (per wave: 64 cols) ----
    // C/D layout (verified m89): col = lane&15, row = (lane>>4)*4 + reg.
    float ckv[4];
    #pragma unroll
    for (int cf = 0; cf < 4; ++cf) ckv[cf] = sCk[w * 64 + cf * 16 + lm];

    #pragma unroll
    for (int rf = 0; rf < 4; ++rf) {
        #pragma unroll
        for (int reg = 0; reg < 4; ++reg) {
            int row = rf * 16 + lh * 4 + reg;
            float jv[4];
            float m = -INFINITY; int am = 0;
            #pragma unroll
            for (int cf = 0; cf < 4; ++cf) {
                float v = fmaf(-0.5f, acc[rf][cf][reg], ckv[cf]);
                jv[cf] = v;
                int col = w * 64 + cf * 16 + lm;
                if (v > m) { m = v; am = col; }    // cf ascending => first-max kept
            }
            #pragma unroll
            for (int o = 1; o < 16; o <<= 1) {
                float om = __shfl_xor(m, o, 16);
                int   oa = __shfl_xor(am, o, 16);
                if (om > m || (om == m && oa < am)) { m = om; am = oa; }
            }
            float es = 0.0f, qs = 0.0f;
            #pragma unroll
            for (int cf = 0; cf < 4; ++cf) {
                float e = expf(jv[cf] - m);
                es += e; qs = fmaf(e, jv[cf], qs);
            }
            #pragma unroll
            for (int o = 1; o < 16; o <<= 1) {
                es += __shfl_xor(es, o, 16);
                qs += __shfl_xor(qs, o, 16);
            }
            if (lm == 0) {
                sMax[row][w] = m; sAm[row][w] = am;
                sEs [row][w] = es; sQs[row][w] = qs;
            }
        }
    }
    __syncthreads();

    // ---- epilogue 2: cross-wave online-softmax merge, one thread per row ----
    if (tid < BN) {
        const int row = tid;
        float m = sMax[row][0]; int am = sAm[row][0];
        float es = sEs[row][0], qs = sQs[row][0];
        #pragma unroll
        for (int w2 = 1; w2 < 4; ++w2) {
            float mw = sMax[row][w2];
            if (mw > m) {
                float f = expf(m - mw);
                es = es * f + sEs[row][w2];
                qs = qs * f + sQs[row][w2];
                m = mw; am = sAm[row][w2];
            } else {
                float f = expf(mw - m);
                es += sEs[row][w2] * f;
                qs += sQs[row][w2] * f;
            }
        }
        sIdx[row] = am;
        float q = qs / es;
        #pragma unroll
        for (int o = 1; o < 64; o <<= 1) q += __shfl_xor(q, o, 64);
        if (tid == 0) atomicAdd(wsq, (double)q);
    }
    __syncthreads();

    // ---- epilogue 3: wave-contiguous resample writes ----
    const int wv = tid >> 6, lane = tid & 63;
    #pragma unroll 4
    for (int r16 = 0; r16 < 16; ++r16) {
        const int row = wv * 16 + r16;
        const int idx = sIdx[row];
        const long n = n0 + row;
        float2 mv = *(const float2*)&means[idx * D_DIM + lane * 2];
        float2 sv = *(const float2*)&sigma[idx * D_DIM + lane * 2];
        float2 nv = *(const float2*)&noise[n * D_DIM + lane * 2];
        float2 ov;
        ov.x = mv.x + sv.x * nv.x * 0.1f;
        ov.y = mv.y + sv.y * nv.y * 0.1f;
        *(float2*)&out_x[n * D_DIM + lane * 2] = ov;
    }
    if (tid < BN) out_idx[n0 + tid] = (float)sIdx[tid];
}

__global__ void gmm_finalize(const double* __restrict__ wsq, float* __restrict__ out_q)
{
    *out_q = (float)(*wsq * (1.0 / ((double)N_ROWS * (double)K_COMP)));
}

extern "C" void kernel_launch(void* const* d_in, const int* in_sizes, int n_in,
                              void* d_out, int out_size, void* d_ws, size_t ws_size,
                              hipStream_t stream)
{
    const float* x        = (const float*)d_in[0];
    const float* means    = (const float*)d_in[1];
    const float* log_stds = (const float*)d_in[2];
    const float* weights  = (const float*)d_in[3];
    const float* noise    = (const float*)d_in[4];

    float* out_x   = (float*)d_out;                          // [N, D]
    float* out_idx = (float*)d_out + (size_t)N_ROWS * D_DIM; // [N]
    float* out_q   = out_idx + N_ROWS;                       // scalar

    // ws layout (floats): Bhi[64K halves = 32768 f] | Blo[32768 f] |
    //                     sigma[32768] | ck[256] | (double) wsq
    float*     ws    = (float*)d_ws;
    _Float16*  Bhi   = (_Float16*)ws;
    _Float16*  Blo   = (_Float16*)(ws + 32768);
    float*     sigma = ws + 65536;
    float*     ckp   = ws + 98304;
    double*    wsq   = (double*)(ws + 98560);

    hipLaunchKernelGGL(gmm_prep, dim3(K_COMP), dim3(D_DIM), 0, stream,
                       means, log_stds, weights, Bhi, Blo, sigma, ckp, wsq);
    hipLaunchKernelGGL(gmm_main, dim3(N_ROWS / BN), dim3(256), 0, stream,
                       x, noise, means, sigma, Bhi, Blo, ckp, out_x, out_idx, wsq);
    hipLaunchKernelGGL(gmm_finalize, dim3(1), dim3(1), 0, stream, wsq, out_q);
}